// Round 16
// baseline (330.224 us; speedup 1.0000x reference)
//
#include <hip/hip_runtime.h>
#include <hip/hip_bf16.h>

typedef unsigned short u16;
typedef unsigned int u32;
using short8 = __attribute__((ext_vector_type(8))) short;
using f32x4  = __attribute__((ext_vector_type(4))) float;

#define T_   64
#define D_   300
#define H_   256
#define G_   768            // 3H
#define NROW 512            // useful sequences (s==2)
#define M_   (NROW * T_)    // 32768
#define KP_  320            // K=300 padded to 320 for MFMA

__device__ __forceinline__ float bf2f(u16 v) {
    union { u32 u; float f; } x; x.u = ((u32)v) << 16; return x.f;
}
__device__ __forceinline__ float bf2f_lo(u32 w) {
    union { u32 u; float f; } x; x.u = w << 16; return x.f;
}
__device__ __forceinline__ float bf2f_hi(u32 w) {
    union { u32 u; float f; } x; x.u = w & 0xFFFF0000u; return x.f;
}
__device__ __forceinline__ u16 f2bf(float f) {
    union { u32 u; float f; } x; x.f = f;
    u32 u = x.u;
    u32 r = (u + 0x7FFFu + ((u >> 16) & 1u)) >> 16;   // RNE
    return (u16)r;
}
__device__ __forceinline__ float frcp(float x) {
    float r; asm("v_rcp_f32 %0, %1" : "=v"(r) : "v"(x)); return r;
}
__device__ __forceinline__ float fsigm(float x) { return frcp(1.f + __expf(-x)); }
__device__ __forceinline__ float ftanh(float x) {
    return 1.f - 2.f * frcp(1.f + __expf(2.f * x));
}
__device__ __forceinline__ float sigm(float x) { return 1.f / (1.f + expf(-x)); }

// ---------------------------------------------------------------------------
// K0: weight prep + combined bias (b_ih1 + b_hh1 for r,z; b_ih1 for n).
// ---------------------------------------------------------------------------
__global__ __launch_bounds__(256) void k0_prep(
    const float* __restrict__ w_ih1, const float* __restrict__ w_hh1,
    const float* __restrict__ b_ih1, const float* __restrict__ b_hh1,
    const float* __restrict__ w2f, const float* __restrict__ w2b,
    const float* __restrict__ wc1,
    u16* __restrict__ wihb, u16* __restrict__ whpk,
    u16* __restrict__ w2ft, u16* __restrict__ w2bt, u16* __restrict__ wc1t,
    float* __restrict__ biasc)
{
    int y = blockIdx.y;
    int tid = blockIdx.x * 256 + threadIdx.x;
    if (y == 0) {
        if (tid < G_ * KP_) {
            int g = tid / KP_, k = tid % KP_;
            wihb[tid] = (k < D_) ? f2bf(w_ih1[g * D_ + k]) : (u16)0;
        }
    } else if (y == 1) {
        if (tid < 48 * 8 * 64) {
            int lane = tid & 63;
            int ks = (tid >> 6) & 7;
            int nt = tid >> 9;
            int g  = nt * 16 + (lane & 15);
            int kb = ks * 32 + ((lane >> 4) << 3);
            union { u16 h[8]; uint4 q; } u;
#pragma unroll
            for (int e = 0; e < 8; ++e) u.h[e] = f2bf(w_hh1[g * H_ + kb + e]);
            *reinterpret_cast<uint4*>(&whpk[(size_t)tid * 8]) = u.q;
        }
    } else if (y == 2 || y == 3) {
        if (tid < G_ * H_) {
            int k = tid / G_, g = tid % G_;
            const float* src = (y == 2) ? w2f : w2b;
            u16* dst = (y == 2) ? w2ft : w2bt;
            dst[tid] = f2bf(src[g * H_ + k]);
        }
    } else {
        if (tid < 512 * 256) {
            int k = tid / 256, o = tid % 256;
            wc1t[tid] = f2bf(wc1[o * 512 + k]);
        }
        if (tid < G_)
            biasc[tid] = b_ih1[tid] + (tid < 2 * H_ ? b_hh1[tid] : 0.f);
    }
}

// ---------------------------------------------------------------------------
// K1 (round-15 version, unchanged): xgw = (x[:,2] @ wihb^T + biasc).
// 512 thr (8 waves 2x4), 128x256 tile, grid (256,3).
// ---------------------------------------------------------------------------
__global__ __launch_bounds__(512) void k1_xgemm(
    const float* __restrict__ x, const u16* __restrict__ wihb,
    const float* __restrict__ biasc, u32* __restrict__ xgw)
{
    __shared__ alignas(16) u16 As[128 * 40];
    __shared__ alignas(16) u16 Bs[256 * 40];
    const int tid = threadIdx.x;
    const int l = tid & 63, wv = tid >> 6;
    const int wrow = wv >> 2, wcol = wv & 3;
    const int row0 = blockIdx.x * 128, col0 = blockIdx.y * 256;

    f32x4 acc[4][4];
#pragma unroll
    for (int i = 0; i < 4; ++i)
#pragma unroll
        for (int j = 0; j < 4; ++j) acc[i][j] = (f32x4){0.f, 0.f, 0.f, 0.f};

    const int ar = tid >> 2, ah = tid & 3;
    const int grow = row0 + ar;
    const int nn = grow >> 6, tt = grow & 63;
    const float* xrow = x + (size_t)(nn * 256 + 128 + tt) * D_;
    const int br = tid >> 1, bh = tid & 1;
    const u16* wrowp = wihb + (size_t)(col0 + br) * KP_;

    for (int k0 = 0; k0 < KP_; k0 += 32) {
        union { u16 h[8]; uint4 q; } u;
        const int kb = k0 + ah * 8;
        if (kb + 7 < D_) {
            const float4 v0 = *reinterpret_cast<const float4*>(xrow + kb);
            const float4 v1 = *reinterpret_cast<const float4*>(xrow + kb + 4);
            u.h[0] = f2bf(v0.x); u.h[1] = f2bf(v0.y); u.h[2] = f2bf(v0.z); u.h[3] = f2bf(v0.w);
            u.h[4] = f2bf(v1.x); u.h[5] = f2bf(v1.y); u.h[6] = f2bf(v1.z); u.h[7] = f2bf(v1.w);
        } else {
#pragma unroll
            for (int e = 0; e < 8; ++e) {
                int k = kb + e;
                u.h[e] = (k < D_) ? f2bf(xrow[k]) : (u16)0;
            }
        }
        *reinterpret_cast<uint4*>(&As[ar * 40 + ah * 8]) = u.q;
        *reinterpret_cast<uint4*>(&Bs[br * 40 + bh * 16]) =
            *reinterpret_cast<const uint4*>(wrowp + k0 + bh * 16);
        *reinterpret_cast<uint4*>(&Bs[br * 40 + bh * 16 + 8]) =
            *reinterpret_cast<const uint4*>(wrowp + k0 + bh * 16 + 8);
        __syncthreads();

        short8 af[4], bf[4];
#pragma unroll
        for (int fi = 0; fi < 4; ++fi)
            af[fi] = *reinterpret_cast<const short8*>(
                &As[(wrow * 64 + fi * 16 + (l & 15)) * 40 + ((l >> 4) << 3)]);
#pragma unroll
        for (int fj = 0; fj < 4; ++fj)
            bf[fj] = *reinterpret_cast<const short8*>(
                &Bs[(wcol * 64 + fj * 16 + (l & 15)) * 40 + ((l >> 4) << 3)]);
#pragma unroll
        for (int fi = 0; fi < 4; ++fi)
#pragma unroll
            for (int fj = 0; fj < 4; ++fj)
                acc[fi][fj] = __builtin_amdgcn_mfma_f32_16x16x32_bf16(
                    af[fi], bf[fj], acc[fi][fj], 0, 0, 0);
        __syncthreads();
    }

    float bias[4];
#pragma unroll
    for (int fj = 0; fj < 4; ++fj)
        bias[fj] = biasc[col0 + wcol * 64 + fj * 16 + (l & 15)];
#pragma unroll
    for (int fi = 0; fi < 4; ++fi)
#pragma unroll
        for (int fjp = 0; fjp < 2; ++fjp) {
            const int cg0 = col0 + wcol * 64 + fjp * 32;
            const int g = cg0 >> 8;
            const int wv8 = (cg0 & 255) >> 5;
            const int word = g * 128 + wv8 * 16 + (l & 15);
#pragma unroll
            for (int q = 0; q < 4; ++q) {
                const int row = row0 + wrow * 64 + fi * 16 + ((l >> 4) << 2) + q;
                const int t = row & 63, n = row >> 6;
                const u32 lo = f2bf(acc[fi][2 * fjp][q] + bias[2 * fjp]);
                const u32 hi = f2bf(acc[fi][2 * fjp + 1][q] + bias[2 * fjp + 1]);
                xgw[((size_t)t * NROW + n) * 384 + word] = lo | (hi << 16);
            }
        }
}

// ---------------------------------------------------------------------------
// K2 v11: round-8 structure, but ALL 48 weight frags (ks0-7) AGPR-pinned
// (192 AGPR/wave; 2 waves x ~320 unified regs = 640 << 2048/SIMD pool) ->
// ZERO LDS weight reads (was 96 b128/step/CU, ~half the LDS pipe). LDS is
// now only the 17 KB h ping-pong. setprio removed (hurts barrier-synced
// loops). t-loop unrolled x2, prefetch buffers consumed directly (no roll).
// ---------------------------------------------------------------------------
__global__ __launch_bounds__(512)
__attribute__((amdgpu_waves_per_eu(2, 2)))
void k2_gru(const u32* __restrict__ xgw, const u16* __restrict__ whpk,
            const float* __restrict__ b_hh, float* __restrict__ mid)
{
    __shared__ u16 hb[2][16 * 264];          // ping-pong, 16,896 B total
    const int tid = threadIdx.x;
    const int l = tid & 63, wv = tid >> 6;   // wv in [0,8)
    const int n0 = blockIdx.x * 8;
    const int c = l & 15, rgrp = l >> 4;
    const int arow = c, klo = rgrp << 3;
    const int aSel = rgrp >> 1;              // 0: lanes 0-31, 1: lanes 32-63
    const int rbase = (rgrp & 1) * 4;        // rows rbase..rbase+3
    const int u = wv * 32 + aSel * 16 + c;   // hidden unit this lane updates

    // weights ks 0..7 (48 x short8 = 192 regs), pinned to AGPRs
    short8 wr[6][8];
#pragma unroll
    for (int gt = 0; gt < 3; ++gt)
#pragma unroll
        for (int a = 0; a < 2; ++a) {
            const int nt = gt * 16 + wv * 2 + a;
#pragma unroll
            for (int ks = 0; ks < 8; ++ks)
                wr[gt * 2 + a][ks] = *reinterpret_cast<const short8*>(
                    &whpk[(size_t)((nt * 8 + ks) * 64 + l) * 8]);
        }
    asm volatile("" :
        "+a"(wr[0][0]),"+a"(wr[0][1]),"+a"(wr[0][2]),"+a"(wr[0][3]),
        "+a"(wr[0][4]),"+a"(wr[0][5]),"+a"(wr[0][6]),"+a"(wr[0][7]),
        "+a"(wr[1][0]),"+a"(wr[1][1]),"+a"(wr[1][2]),"+a"(wr[1][3]),
        "+a"(wr[1][4]),"+a"(wr[1][5]),"+a"(wr[1][6]),"+a"(wr[1][7]));
    asm volatile("" :
        "+a"(wr[2][0]),"+a"(wr[2][1]),"+a"(wr[2][2]),"+a"(wr[2][3]),
        "+a"(wr[2][4]),"+a"(wr[2][5]),"+a"(wr[2][6]),"+a"(wr[2][7]),
        "+a"(wr[3][0]),"+a"(wr[3][1]),"+a"(wr[3][2]),"+a"(wr[3][3]),
        "+a"(wr[3][4]),"+a"(wr[3][5]),"+a"(wr[3][6]),"+a"(wr[3][7]));
    asm volatile("" :
        "+a"(wr[4][0]),"+a"(wr[4][1]),"+a"(wr[4][2]),"+a"(wr[4][3]),
        "+a"(wr[4][4]),"+a"(wr[4][5]),"+a"(wr[4][6]),"+a"(wr[4][7]),
        "+a"(wr[5][0]),"+a"(wr[5][1]),"+a"(wr[5][2]),"+a"(wr[5][3]),
        "+a"(wr[5][4]),"+a"(wr[5][5]),"+a"(wr[5][6]),"+a"(wr[5][7]));

    for (int i = tid; i < 2 * 16 * 264 / 2; i += 512)
        reinterpret_cast<u32*>(hb)[i] = 0;

    const float bhn = b_hh[512 + u];
    u32 xo[4];
#pragma unroll
    for (int q = 0; q < 4; ++q)
        xo[q] = (u32)(n0 + rbase + q) * 384 + wv * 16 + c;
    float h[4] = {0.f, 0.f, 0.f, 0.f};
    const u32 stepw = (u32)NROW * 384;

    // one full GRU step: consume xv (this step's gates), prefetch xn (tload)
    int p = 0;
    auto gstep = [&](u32 (&xv)[3][4], u32 (&xn)[3][4], int tload) {
        // prefetch next step's gates (hidden under this step)
        const u32 tb = (u32)tload * stepw;
#pragma unroll
        for (int q = 0; q < 4; ++q) {
            xn[0][q] = xgw[tb + xo[q]];
            xn[1][q] = xgw[tb + xo[q] + 128];
            xn[2][q] = xgw[tb + xo[q] + 256];
        }

        // MFMA phase: read hb[p]; all weights from AGPRs
        const u16* hbr = hb[p];
        f32x4 acc[6];
#pragma unroll
        for (int m = 0; m < 6; ++m) acc[m] = (f32x4){0.f, 0.f, 0.f, 0.f};
#pragma unroll
        for (int ks = 0; ks < 8; ++ks) {
            const short8 afr = *reinterpret_cast<const short8*>(
                &hbr[arow * 264 + ks * 32 + klo]);
#pragma unroll
            for (int m = 0; m < 6; ++m)
                acc[m] = __builtin_amdgcn_mfma_f32_16x16x32_bf16(
                    afr, wr[m][ks], acc[m], 0, 0, 0);
        }

        // redistribute: lanes>=32 take a=1 accs from lane l-32
        float vr[4], vz[4], vn[4];
#pragma unroll
        for (int q = 0; q < 4; ++q) {
            const float r1 = __shfl(acc[1][q], l & 31);
            const float z1 = __shfl(acc[3][q], l & 31);
            const float n1 = __shfl(acc[5][q], l & 31);
            vr[q] = (l < 32) ? acc[0][q] : r1;
            vz[q] = (l < 32) ? acc[2][q] : z1;
            vn[q] = (l < 32) ? acc[4][q] : n1;
        }

        // update phase: 4 (row,unit) values per lane, all 64 lanes active
        u16* hbw = hb[p ^ 1];
#pragma unroll
        for (int q = 0; q < 4; ++q) {
            const float xr = aSel ? bf2f_hi(xv[0][q]) : bf2f_lo(xv[0][q]);
            const float xz = aSel ? bf2f_hi(xv[1][q]) : bf2f_lo(xv[1][q]);
            const float xn2 = aSel ? bf2f_hi(xv[2][q]) : bf2f_lo(xv[2][q]);
            const float rg = fsigm(xr + vr[q]);
            const float zg = fsigm(xz + vz[q]);
            const float ng = ftanh(xn2 + rg * (vn[q] + bhn));
            h[q] = zg * (h[q] - ng) + ng;
            hbw[(rbase + q) * 264 + u] = f2bf(h[q]);
        }

        // single barrier per step (lgkm only; vmcnt stays in flight)
        asm volatile("s_waitcnt lgkmcnt(0)" ::: "memory");
        __builtin_amdgcn_sched_barrier(0);
        __builtin_amdgcn_s_barrier();
        __builtin_amdgcn_sched_barrier(0);
        p ^= 1;
    };

    // prologue: load t=0 gates
    u32 xa[3][4], xb[3][4];
#pragma unroll
    for (int q = 0; q < 4; ++q) {
        xa[0][q] = xgw[xo[q]];
        xa[1][q] = xgw[xo[q] + 128];
        xa[2][q] = xgw[xo[q] + 256];
    }

    __syncthreads();

    for (int t = 0; t < T_; t += 2) {
        gstep(xa, xb, t + 1);                              // consume xa
        gstep(xb, xa, (t + 2 < T_) ? t + 2 : T_ - 1);      // consume xb
    }

#pragma unroll
    for (int q = 0; q < 4; ++q)
        mid[(size_t)(n0 + rbase + q) * H_ + u] = h[q];
}

// ---------------------------------------------------------------------------
// K3: head. (unchanged)
// ---------------------------------------------------------------------------
__global__ __launch_bounds__(256) void k3_head(
    const float* __restrict__ mid,
    const u16* __restrict__ w2ft, const u16* __restrict__ w2bt,
    const float* __restrict__ b_ih2f, const float* __restrict__ b_hh2f,
    const float* __restrict__ b_ih2b, const float* __restrict__ b_hh2b,
    const u16* __restrict__ wc1t, const float* __restrict__ bc1,
    const float* __restrict__ wc2, const float* __restrict__ bc2,
    float* __restrict__ out)
{
    __shared__ float m[4][H_];
    __shared__ float xg2[2][4][G_];
    __shared__ float emb[4][512];
    __shared__ float hid[4][H_];
    int tid = threadIdx.x;
    int r0 = blockIdx.x * 4;

    for (int i = tid; i < 4 * H_; i += 256) {
        int r = i >> 8, k = i & 255;
        m[r][k] = mid[(size_t)(r0 + r) * H_ + k];
    }
    __syncthreads();

    const int g0 = tid, g1 = tid + 256, g2 = tid + 512;
    float bf0 = b_ih2f[g0] + b_hh2f[g0];
    float bf1 = b_ih2f[g1] + b_hh2f[g1];
    float bf2v = b_ih2f[g2];
    float bb0 = b_ih2b[g0] + b_hh2b[g0];
    float bb1 = b_ih2b[g1] + b_hh2b[g1];
    float bb2v = b_ih2b[g2];
    float af[4][3], ab[4][3];
#pragma unroll
    for (int r = 0; r < 4; ++r) {
        af[r][0] = bf0; af[r][1] = bf1; af[r][2] = bf2v;
        ab[r][0] = bb0; ab[r][1] = bb1; ab[r][2] = bb2v;
    }
#pragma unroll 4
    for (int k = 0; k < H_; ++k) {
        float wf0 = bf2f(w2ft[k * G_ + g0]);
        float wf1 = bf2f(w2ft[k * G_ + g1]);
        float wf2 = bf2f(w2ft[k * G_ + g2]);
        float wb0 = bf2f(w2bt[k * G_ + g0]);
        float wb1 = bf2f(w2bt[k * G_ + g1]);
        float wb2 = bf2f(w2bt[k * G_ + g2]);
#pragma unroll
        for (int r = 0; r < 4; ++r) {
            float mm = m[r][k];
            af[r][0] += mm * wf0; af[r][1] += mm * wf1; af[r][2] += mm * wf2;
            ab[r][0] += mm * wb0; ab[r][1] += mm * wb1; ab[r][2] += mm * wb2;
        }
    }
#pragma unroll
    for (int r = 0; r < 4; ++r) {
        xg2[0][r][g0] = af[r][0]; xg2[0][r][g1] = af[r][1]; xg2[0][r][g2] = af[r][2];
        xg2[1][r][g0] = ab[r][0]; xg2[1][r][g1] = ab[r][1]; xg2[1][r][g2] = ab[r][2];
    }
    __syncthreads();

    {
        const int j = tid;
        float bnf = b_hh2f[512 + j], bnb = b_hh2b[512 + j];
#pragma unroll
        for (int r = 0; r < 4; ++r) {
            float rg = sigm(xg2[0][r][j]);
            float zg = sigm(xg2[0][r][256 + j]);
            float ng = tanhf(xg2[0][r][512 + j] + rg * bnf);
            emb[r][j] = (1.f - zg) * ng;
            rg = sigm(xg2[1][r][j]);
            zg = sigm(xg2[1][r][256 + j]);
            ng = tanhf(xg2[1][r][512 + j] + rg * bnb);
            emb[r][256 + j] = (1.f - zg) * ng;
        }
    }
    __syncthreads();

    {
        const int o = tid;
        float acc[4];
        float b = bc1[o];
#pragma unroll
        for (int r = 0; r < 4; ++r) acc[r] = b;
#pragma unroll 4
        for (int k = 0; k < 512; ++k) {
            float w = bf2f(wc1t[k * H_ + o]);
#pragma unroll
            for (int r = 0; r < 4; ++r) acc[r] += emb[r][k] * w;
        }
#pragma unroll
        for (int r = 0; r < 4; ++r) {
            float pre = acc[r];
            hid[r][o] = pre >= 0.f ? pre : 0.1f * pre;
        }
    }
    __syncthreads();

    {
        int grp = tid >> 5, lane = tid & 31;
        int r = grp >> 1, cc = grp & 1;
        float s = 0.f;
        for (int k = lane; k < H_; k += 32) s += hid[r][k] * wc2[cc * H_ + k];
#pragma unroll
        for (int msk = 16; msk >= 1; msk >>= 1) s += __shfl_xor(s, msk, 32);
        if (lane == 0) out[(size_t)(r0 + r) * 2 + cc] = s + bc2[cc];
    }
}

// ---------------------------------------------------------------------------
extern "C" void kernel_launch(void* const* d_in, const int* in_sizes, int n_in,
                              void* d_out, int out_size, void* d_ws, size_t ws_size,
                              hipStream_t stream)
{
    const float* x      = (const float*)d_in[0];
    const float* w_ih1  = (const float*)d_in[1];
    const float* w_hh1  = (const float*)d_in[2];
    const float* b_ih1  = (const float*)d_in[3];
    const float* b_hh1  = (const float*)d_in[4];
    const float* w_ih2f = (const float*)d_in[5];
    const float* b_ih2f = (const float*)d_in[7];
    const float* b_hh2f = (const float*)d_in[8];
    const float* w_ih2b = (const float*)d_in[9];
    const float* b_ih2b = (const float*)d_in[11];
    const float* b_hh2b = (const float*)d_in[12];
    const float* wc1    = (const float*)d_in[13];
    const float* bc1    = (const float*)d_in[14];
    const float* wc2    = (const float*)d_in[15];
    const float* bc2    = (const float*)d_in[16];
    float* out = (float*)d_out;

    char* p = (char*)d_ws;
    u32* xgw  = (u32*)p;  p += (size_t)M_ * 384 * 4;         // 48 MB [t][n][3][128]u32
    u16* wihb = (u16*)p;  p += (size_t)G_ * KP_ * 2;         // 480 KB
    u16* whpk = (u16*)p;  p += (size_t)48 * 8 * 64 * 8 * 2;  // 384 KB
    u16* w2ft = (u16*)p;  p += (size_t)G_ * H_ * 2;
    u16* w2bt = (u16*)p;  p += (size_t)G_ * H_ * 2;
    u16* wc1t = (u16*)p;  p += (size_t)512 * 256 * 2;
    float* mid = (float*)p; p += (size_t)NROW * H_ * 4;
    float* biasc = (float*)p; p += (size_t)G_ * 4;

    k0_prep<<<dim3(960, 5), 256, 0, stream>>>(w_ih1, w_hh1, b_ih1, b_hh1,
                                              w_ih2f, w_ih2b, wc1,
                                              wihb, whpk, w2ft, w2bt, wc1t, biasc);
    k1_xgemm<<<dim3(M_ / 128, 3), 512, 0, stream>>>(x, wihb, biasc, xgw);
    k2_gru<<<64, 512, 0, stream>>>(xgw, whpk, b_hh1, mid);
    k3_head<<<128, 256, 0, stream>>>(mid, w2ft, w2bt, b_ih2f, b_hh2f,
                                     b_ih2b, b_hh2b, wc1t, bc1, wc2, bc2, out);
}